// Round 1
// baseline (1090.746 us; speedup 1.0000x reference)
//
#include <hip/hip_runtime.h>

typedef __bf16 bf16_t;
typedef __bf16 bf16x8 __attribute__((ext_vector_type(8)));
typedef __bf16 bf16x4 __attribute__((ext_vector_type(4)));
typedef float  f32x4  __attribute__((ext_vector_type(4)));
typedef short  s16x4  __attribute__((ext_vector_type(4)));

#define SEQ   1024
#define DMODEL 4096
#define NHQ   32
#define NHKV  8
#define HDIM  128

// ---------------------------------------------------------------------------
// GEMM: C[M][N] = A[M][K] * B[N][K]^T   (both K-contiguous, "gemm_bt")
// 128x128 tile, BK=32, 4 waves (2x2 of 64x64), 16x16x32 bf16 MFMA.
// A is fp32 (QKV proj) or bf16 (final proj); B (weights) always fp32.
// fp32->bf16 conversion happens in registers during LDS staging.
// LDS rows padded to 40 elems (80B): lanes' b128 frag reads are 2-way (free).
// ---------------------------------------------------------------------------
template<bool A_BF16, bool OUT_F32>
__global__ __launch_bounds__(256, 2)
void gemm_bt(const void* __restrict__ Av, const float* __restrict__ Bw,
             void* __restrict__ Cv, int M, int N, int K, int nbn)
{
    __shared__ __align__(16) bf16_t lA[128 * 40];
    __shared__ __align__(16) bf16_t lB[128 * 40];

    const int bid = blockIdx.x;
    const int bm = bid / nbn, bn = bid % nbn;
    const int t = threadIdx.x;
    const int lane = t & 63, wid = t >> 6;
    const int wrow = (wid >> 1) * 64, wcol = (wid & 1) * 64;
    const int l15 = lane & 15, lg = lane >> 4;
    const int m0 = bm * 128, n0 = bn * 128;

    f32x4 acc[4][4] = {};

    for (int k0 = 0; k0 < K; k0 += 32) {
        __syncthreads();   // previous tile fully consumed
        // ---- stage A tile (128x32) ----
        if constexpr (A_BF16) {
            const bf16_t* A = (const bf16_t*)Av;
            #pragma unroll
            for (int i = 0; i < 2; ++i) {
                int idx = t + 256 * i;              // 512 chunks of 8 bf16
                int r = idx >> 2, c8 = (idx & 3) * 8;
                bf16x8 v = *(const bf16x8*)(A + (size_t)(m0 + r) * K + k0 + c8);
                *(bf16x8*)(lA + r * 40 + c8) = v;
            }
        } else {
            const float* A = (const float*)Av;
            #pragma unroll
            for (int i = 0; i < 4; ++i) {
                int idx = t + 256 * i;              // 1024 chunks of 4 floats
                int r = idx >> 3, c4 = (idx & 7) * 4;
                float4 v = *(const float4*)(A + (size_t)(m0 + r) * K + k0 + c4);
                bf16x4 bb;
                bb[0] = (bf16_t)v.x; bb[1] = (bf16_t)v.y;
                bb[2] = (bf16_t)v.z; bb[3] = (bf16_t)v.w;
                *(bf16x4*)(lA + r * 40 + c4) = bb;
            }
        }
        // ---- stage B tile (128x32, always fp32 weights) ----
        #pragma unroll
        for (int i = 0; i < 4; ++i) {
            int idx = t + 256 * i;
            int r = idx >> 3, c4 = (idx & 7) * 4;
            float4 v = *(const float4*)(Bw + (size_t)(n0 + r) * K + k0 + c4);
            bf16x4 bb;
            bb[0] = (bf16_t)v.x; bb[1] = (bf16_t)v.y;
            bb[2] = (bf16_t)v.z; bb[3] = (bf16_t)v.w;
            *(bf16x4*)(lB + r * 40 + c4) = bb;
        }
        __syncthreads();
        // ---- fragments + MFMA ----
        bf16x8 af[4], bfr[4];
        #pragma unroll
        for (int m = 0; m < 4; ++m)
            af[m] = *(const bf16x8*)(lA + (wrow + m * 16 + l15) * 40 + lg * 8);
        #pragma unroll
        for (int n = 0; n < 4; ++n)
            bfr[n] = *(const bf16x8*)(lB + (wcol + n * 16 + l15) * 40 + lg * 8);
        #pragma unroll
        for (int m = 0; m < 4; ++m)
            #pragma unroll
            for (int n = 0; n < 4; ++n)
                acc[m][n] = __builtin_amdgcn_mfma_f32_16x16x32_bf16(
                    af[m], bfr[n], acc[m][n], 0, 0, 0);
    }
    // ---- epilogue: D col = lane&15, row = (lane>>4)*4 + i  (m89-verified) ----
    #pragma unroll
    for (int m = 0; m < 4; ++m) {
        #pragma unroll
        for (int n = 0; n < 4; ++n) {
            int col = n0 + wcol + n * 16 + l15;
            #pragma unroll
            for (int i = 0; i < 4; ++i) {
                int row = m0 + wrow + m * 16 + lg * 4 + i;
                if constexpr (OUT_F32)
                    ((float*)Cv)[(size_t)row * N + col] = acc[m][n][i];
                else
                    ((bf16_t*)Cv)[(size_t)row * N + col] = (bf16_t)acc[m][n][i];
            }
        }
    }
}

// ---------------------------------------------------------------------------
// RoPE (interleaved pairs), in-place on bf16 Q or K.
// idx -> (tok, head, j) ; pair = elements (2j, 2j+1) ; cos/sin[s][j] fp32.
// ---------------------------------------------------------------------------
__global__ __launch_bounds__(256)
void rope_kernel(bf16_t* __restrict__ X, const float* __restrict__ fc,
                 const float* __restrict__ fs, int nheads)
{
    int idx = blockIdx.x * 256 + threadIdx.x;
    int j = idx & 63;
    int rest = idx >> 6;
    int h = rest % nheads;
    int tok = rest / nheads;
    int s = tok & (SEQ - 1);
    size_t base = ((size_t)tok * nheads + h) * HDIM + 2 * j;
    float c = fc[s * 64 + j], sn = fs[s * 64 + j];
    float x0 = (float)X[base], x1 = (float)X[base + 1];
    X[base]     = (bf16_t)(x0 * c - x1 * sn);
    X[base + 1] = (bf16_t)(x0 * sn + x1 * c);
}

// ---------------------------------------------------------------------------
// Flash attention (non-causal, full 1024 keys), GQA 4:1.
// Block = 4 waves, 64 q-rows (16 per wave), one (b,h); 16 K/V tiles of 64.
// Swapped QK^T: S^T[key][q] via mfma(Kfrag, Qfrag) -> softmax per-lane
// (q = lane&15), P^T regs feed mfma_f32_16x16x16bf16_1k directly as A.
// V staged transposed in LDS with XOR swizzle (((d>>3)&7)<<4) so both the
// scalar transpose writes and the b64 fragment reads are ~2-way conflict free.
// ---------------------------------------------------------------------------
__global__ __launch_bounds__(256, 2)
void attn_kernel(const bf16_t* __restrict__ Q, const bf16_t* __restrict__ K,
                 const bf16_t* __restrict__ V, bf16_t* __restrict__ O)
{
    __shared__ __align__(16) bf16_t kl[64 * 136];      // K tile, row stride 136 elems
    __shared__ __align__(16) char  vtb[128 * 136];     // V^T tile, row stride 136 BYTES

    const int blk = blockIdx.x;
    const int qt = blk & 15;          // q-tile 0..15
    const int bh = blk >> 4;          // 0..127
    const int b = bh >> 5, h = bh & 31, kv = h >> 2;
    const int t = threadIdx.x, lane = t & 63, wid = t >> 6;
    const int l15 = lane & 15, lg = lane >> 4;

    const float SCL = 0.08838834764831845f;   // 1/sqrt(128)
    const float L2E = 1.4426950408889634f;

    // Q fragments (held in registers for all tiles): q = lane&15's row
    const int qrow = qt * 64 + wid * 16 + l15;
    const size_t qbase = (((size_t)(b * SEQ + qrow)) * NHQ + h) * HDIM;
    bf16x8 qf[4];
    #pragma unroll
    for (int dc = 0; dc < 4; ++dc)
        qf[dc] = *(const bf16x8*)(Q + qbase + dc * 32 + lg * 8);

    f32x4 o[8] = {};                  // O[q=(lg*4+i)][d=l15+16*db]
    float mrun = -3.0e38f, lrun = 0.f;

    for (int kt = 0; kt < 16; ++kt) {
        __syncthreads();
        // ---- stage K (row-major) and V (transposed + swizzled) ----
        #pragma unroll
        for (int i = 0; i < 4; ++i) {
            int idx = t + 256 * i;
            int r = idx >> 4, c8 = (idx & 15) * 8;
            size_t src = (((size_t)(b * SEQ + kt * 64 + r)) * NHKV + kv) * HDIM + c8;
            *(bf16x8*)(kl + r * 136 + c8) = *(const bf16x8*)(K + src);
            bf16x8 v8 = *(const bf16x8*)(V + src);
            #pragma unroll
            for (int jj = 0; jj < 8; ++jj) {
                int d = c8 + jj;
                int off = d * 136 + ((r * 2) ^ (((d >> 3) & 7) << 4));
                *(bf16_t*)(vtb + off) = v8[jj];
            }
        }
        __syncthreads();

        // ---- QK^T -> S^T[key][q] (A = K rows, B = Q) ----
        f32x4 sacc[4] = {};
        #pragma unroll
        for (int kb = 0; kb < 4; ++kb)
            #pragma unroll
            for (int dc = 0; dc < 4; ++dc) {
                bf16x8 kf = *(const bf16x8*)(kl + (kb * 16 + l15) * 136 + dc * 32 + lg * 8);
                sacc[kb] = __builtin_amdgcn_mfma_f32_16x16x32_bf16(
                    kf, qf[dc], sacc[kb], 0, 0, 0);
            }

        // ---- online softmax (per lane: fixed q = l15; 16 keys held) ----
        float sv[16];
        float mt = -3.0e38f;
        #pragma unroll
        for (int kb = 0; kb < 4; ++kb)
            #pragma unroll
            for (int i = 0; i < 4; ++i) {
                float s = sacc[kb][i] * SCL;
                sv[kb * 4 + i] = s;
                mt = fmaxf(mt, s);
            }
        mt = fmaxf(mt, __shfl_xor(mt, 16));
        mt = fmaxf(mt, __shfl_xor(mt, 32));
        float mnew = fmaxf(mrun, mt);
        float alpha = exp2f((mrun - mnew) * L2E);

        float ts = 0.f;
        s16x4 pf[4];
        #pragma unroll
        for (int kb = 0; kb < 4; ++kb)
            #pragma unroll
            for (int i = 0; i < 4; ++i) {
                float p = exp2f((sv[kb * 4 + i] - mnew) * L2E);
                ts += p;
                pf[kb][i] = (short)__builtin_bit_cast(unsigned short, (bf16_t)p);
            }
        ts += __shfl_xor(ts, 16);
        ts += __shfl_xor(ts, 32);
        lrun = lrun * alpha + ts;
        mrun = mnew;

        // ---- rescale O (row q = lg*4+i needs alpha from lane q) ----
        #pragma unroll
        for (int i = 0; i < 4; ++i) {
            float ai = __shfl(alpha, lg * 4 + i);
            #pragma unroll
            for (int db = 0; db < 8; ++db) o[db][i] *= ai;
        }

        // ---- PV: O[q][d] += P^T-regs (A) * V^T-lds (B), 16x16x16 bf16 ----
        #pragma unroll
        for (int kb = 0; kb < 4; ++kb)
            #pragma unroll
            for (int db = 0; db < 8; ++db) {
                int d = l15 + 16 * db;
                int key0 = kb * 16 + lg * 4;
                int off = d * 136 + ((key0 * 2) ^ (((d >> 3) & 7) << 4));
                s16x4 vf = *(const s16x4*)(vtb + off);
                o[db] = __builtin_amdgcn_mfma_f32_16x16x16bf16_1k(
                    pf[kb], vf, o[db], 0, 0, 0);
            }
    }

    // ---- epilogue: divide by l, store bf16 ----
    #pragma unroll
    for (int i = 0; i < 4; ++i) {
        float li = __shfl(lrun, lg * 4 + i);
        float inv = 1.0f / li;
        int row = b * SEQ + qt * 64 + wid * 16 + lg * 4 + i;
        #pragma unroll
        for (int db = 0; db < 8; ++db) {
            int col = h * HDIM + l15 + 16 * db;
            O[(size_t)row * DMODEL + col] = (bf16_t)(o[db][i] * inv);
        }
    }
}

// ---------------------------------------------------------------------------
// Launch: QKV proj -> RoPE(Q,K) -> flash attn -> output proj.
// start_pos == 0 and caches are zero => plain full self-attention; cache
// inputs are never read or written (inputs must not be mutated).
// Workspace: Q 32MB | K 8MB | V 8MB | attn_out 32MB  (~84MB of d_ws, bf16).
// ---------------------------------------------------------------------------
extern "C" void kernel_launch(void* const* d_in, const int* in_sizes, int n_in,
                              void* d_out, int out_size, void* d_ws, size_t ws_size,
                              hipStream_t stream)
{
    const float* x  = (const float*)d_in[0];
    const float* wq = (const float*)d_in[1];
    const float* wk = (const float*)d_in[2];
    const float* wv = (const float*)d_in[3];
    const float* wo = (const float*)d_in[4];
    const float* fc = (const float*)d_in[5];
    const float* fs = (const float*)d_in[6];

    bf16_t* Qw = (bf16_t*)d_ws;                       // [4096][4096]
    bf16_t* Kw = Qw + (size_t)4096 * 4096;            // [4096][1024]
    bf16_t* Vw = Kw + (size_t)4096 * 1024;            // [4096][1024]
    bf16_t* AO = Vw + (size_t)4096 * 1024;            // [4096][4096]

    gemm_bt<false, false><<<1024, 256, 0, stream>>>(x, wq, Qw, 4096, 4096, 4096, 32);
    gemm_bt<false, false><<<256,  256, 0, stream>>>(x, wk, Kw, 4096, 1024, 4096, 8);
    gemm_bt<false, false><<<256,  256, 0, stream>>>(x, wv, Vw, 4096, 1024, 4096, 8);
    rope_kernel<<<32768, 256, 0, stream>>>(Qw, fc, fs, NHQ);
    rope_kernel<<<8192,  256, 0, stream>>>(Kw, fc, fs, NHKV);
    attn_kernel<<<2048, 256, 0, stream>>>(Qw, Kw, Vw, AO);
    gemm_bt<true, true><<<1024, 256, 0, stream>>>(AO, wo, d_out, 4096, 4096, 4096, 32);
}

// Round 2
// 692.750 us; speedup vs baseline: 1.5745x; 1.5745x over previous
//
#include <hip/hip_runtime.h>

typedef __bf16 bf16_t;
typedef __bf16 bf16x8 __attribute__((ext_vector_type(8)));
typedef float  f32x4  __attribute__((ext_vector_type(4)));
typedef short  s16x4  __attribute__((ext_vector_type(4)));

#define SEQ    1024
#define DMODEL 4096
#define NHQ    32
#define NHKV   8
#define HDIM   128

// async global->LDS, 16B per lane; LDS dest must be linear (base + lane*16)
#define GLOAD_LDS16(g, l)                                                  \
    __builtin_amdgcn_global_load_lds(                                      \
        (const __attribute__((address_space(1))) unsigned int*)(g),        \
        (__attribute__((address_space(3))) unsigned int*)(l), 16, 0, 0)

// ---------------------------------------------------------------------------
// fp32 -> bf16 convert, 8 elems/thread (2x float4 in, bf16x8 out)
// ---------------------------------------------------------------------------
__global__ __launch_bounds__(256)
void f2b(const float* __restrict__ in, bf16_t* __restrict__ out, int n8)
{
    int i = blockIdx.x * 256 + threadIdx.x;
    if (i >= n8) return;
    const float4* p = (const float4*)in + 2 * (size_t)i;
    float4 a = p[0], b = p[1];
    bf16x8 o;
    o[0] = (bf16_t)a.x; o[1] = (bf16_t)a.y; o[2] = (bf16_t)a.z; o[3] = (bf16_t)a.w;
    o[4] = (bf16_t)b.x; o[5] = (bf16_t)b.y; o[6] = (bf16_t)b.z; o[7] = (bf16_t)b.w;
    *((bf16x8*)out + i) = o;
}

// ---------------------------------------------------------------------------
// GEMM: C[M][N] = A[M][K] * B[N][K]^T, all bf16 in, bf16 or f32 out.
// m97 structure: 128x128 tile, BK=32, 4 waves (2x2 of 64x64), 16x16x32 MFMA,
// global_load_lds width=16 staging into LINEAR LDS, 2-barrier K-loop,
// bijective XCD swizzle (grids here are all % 8 == 0).
// ---------------------------------------------------------------------------
template<bool OUT_F32>
__global__ __launch_bounds__(256, 2)
void gemm_bt(const bf16_t* __restrict__ A, const bf16_t* __restrict__ B,
             void* __restrict__ Cv, int M, int N, int K, int nbn)
{
    __shared__ __align__(16) bf16_t lA[128 * 32];
    __shared__ __align__(16) bf16_t lB[128 * 32];

    const int nwg = gridDim.x;
    const int bid0 = blockIdx.x;
    const int bid = (bid0 & 7) * (nwg >> 3) + (bid0 >> 3);   // XCD swizzle
    const int bm = bid / nbn, bn = bid % nbn;
    const int t = threadIdx.x;
    const int lane = t & 63, wid = t >> 6;
    const int wrow = (wid >> 1) * 64, wcol = (wid & 1) * 64;
    const int l15 = lane & 15, lg = lane >> 4;
    const int m0 = bm * 128, n0 = bn * 128;

    // staging: 512 chunks of 16B per tile; chunk c -> row c>>2, 8-elem pos c&3
    const int r0 = t >> 2, pos0 = (t & 3) * 8;
    const int r1 = r0 + 64;

    const bf16_t* Ar0 = A + (size_t)(m0 + r0) * K + pos0;
    const bf16_t* Ar1 = A + (size_t)(m0 + r1) * K + pos0;
    const bf16_t* Br0 = B + (size_t)(n0 + r0) * K + pos0;
    const bf16_t* Br1 = B + (size_t)(n0 + r1) * K + pos0;

    f32x4 acc[4][4] = {};

    for (int k0 = 0; k0 < K; k0 += 32) {
        __syncthreads();                       // prev tile fully consumed
        GLOAD_LDS16(Ar0 + k0, lA + t * 8);
        GLOAD_LDS16(Ar1 + k0, lA + (t + 256) * 8);
        GLOAD_LDS16(Br0 + k0, lB + t * 8);
        GLOAD_LDS16(Br1 + k0, lB + (t + 256) * 8);
        __syncthreads();                       // barrier drains vmcnt(0)

        bf16x8 af[4], bfr[4];
        #pragma unroll
        for (int m = 0; m < 4; ++m)
            af[m] = *(const bf16x8*)(lA + (wrow + m * 16 + l15) * 32 + lg * 8);
        #pragma unroll
        for (int n = 0; n < 4; ++n)
            bfr[n] = *(const bf16x8*)(lB + (wcol + n * 16 + l15) * 32 + lg * 8);
        #pragma unroll
        for (int m = 0; m < 4; ++m)
            #pragma unroll
            for (int n = 0; n < 4; ++n)
                acc[m][n] = __builtin_amdgcn_mfma_f32_16x16x32_bf16(
                    af[m], bfr[n], acc[m][n], 0, 0, 0);
    }

    // D layout (m89): col = lane&15, row = (lane>>4)*4 + i
    #pragma unroll
    for (int m = 0; m < 4; ++m) {
        #pragma unroll
        for (int n = 0; n < 4; ++n) {
            int col = n0 + wcol + n * 16 + l15;
            #pragma unroll
            for (int i = 0; i < 4; ++i) {
                int row = m0 + wrow + m * 16 + lg * 4 + i;
                if constexpr (OUT_F32)
                    ((float*)Cv)[(size_t)row * N + col] = acc[m][n][i];
                else
                    ((bf16_t*)Cv)[(size_t)row * N + col] = (bf16_t)acc[m][n][i];
            }
        }
    }
}

// ---------------------------------------------------------------------------
// RoPE (interleaved pairs), in-place on bf16, 8 elems (4 pairs) per thread.
// rowstride = elements per token row (Q: 4096, K-in-KV: 2048).
// ---------------------------------------------------------------------------
__global__ __launch_bounds__(256)
void rope_kernel(bf16_t* __restrict__ X, const float* __restrict__ fc,
                 const float* __restrict__ fs, int nheads, int rowstride)
{
    int idx = blockIdx.x * 256 + threadIdx.x;   // tok*heads*16
    int j4 = idx & 15;
    int rest = idx >> 4;
    int h = rest % nheads;
    int tok = rest / nheads;
    int s = tok & (SEQ - 1);
    bf16_t* p = X + (size_t)tok * rowstride + h * HDIM + j4 * 8;
    bf16x8 v = *(const bf16x8*)p;
    float4 c  = *(const float4*)(fc + s * 64 + j4 * 4);
    float4 sn = *(const float4*)(fs + s * 64 + j4 * 4);
    bf16x8 o;
    o[0] = (bf16_t)((float)v[0] * c.x - (float)v[1] * sn.x);
    o[1] = (bf16_t)((float)v[0] * sn.x + (float)v[1] * c.x);
    o[2] = (bf16_t)((float)v[2] * c.y - (float)v[3] * sn.y);
    o[3] = (bf16_t)((float)v[2] * sn.y + (float)v[3] * c.y);
    o[4] = (bf16_t)((float)v[4] * c.z - (float)v[5] * sn.z);
    o[5] = (bf16_t)((float)v[4] * sn.z + (float)v[5] * c.z);
    o[6] = (bf16_t)((float)v[6] * c.w - (float)v[7] * sn.w);
    o[7] = (bf16_t)((float)v[6] * sn.w + (float)v[7] * c.w);
    *(bf16x8*)p = o;
}

// ---------------------------------------------------------------------------
// Flash attention (non-causal), GQA 4:1. KV layout: [tok][ K(8x128) | V(8x128) ]
// row stride 2048. Swapped QK^T (S^T via mfma(K,Q)), in-register softmax,
// P^T regs feed 16x16x16 bf16 MFMA as A; V^T staged in LDS with XOR swizzle.
// ---------------------------------------------------------------------------
__global__ __launch_bounds__(256, 2)
void attn_kernel(const bf16_t* __restrict__ Q, const bf16_t* __restrict__ KV,
                 bf16_t* __restrict__ O)
{
    __shared__ __align__(16) bf16_t kl[64 * 136];      // K tile, row stride 136 elems
    __shared__ __align__(16) char  vtb[128 * 136];     // V^T tile, row stride 136 BYTES

    const int blk = blockIdx.x;
    const int qt = blk & 15;
    const int bh = blk >> 4;
    const int b = bh >> 5, h = bh & 31, kv = h >> 2;
    const int t = threadIdx.x, lane = t & 63, wid = t >> 6;
    const int l15 = lane & 15, lg = lane >> 4;

    const float SCL = 0.08838834764831845f;   // 1/sqrt(128)
    const float L2E = 1.4426950408889634f;

    const int qrow = qt * 64 + wid * 16 + l15;
    const size_t qbase = (size_t)(b * SEQ + qrow) * DMODEL + h * HDIM;
    bf16x8 qf[4];
    #pragma unroll
    for (int dc = 0; dc < 4; ++dc)
        qf[dc] = *(const bf16x8*)(Q + qbase + dc * 32 + lg * 8);

    f32x4 o[8] = {};
    float mrun = -3.0e38f, lrun = 0.f;

    for (int kt = 0; kt < 16; ++kt) {
        __syncthreads();
        #pragma unroll
        for (int i = 0; i < 4; ++i) {
            int idx = t + 256 * i;
            int r = idx >> 4, c8 = (idx & 15) * 8;
            size_t src = (size_t)(b * SEQ + kt * 64 + r) * 2048 + kv * HDIM + c8;
            *(bf16x8*)(kl + r * 136 + c8) = *(const bf16x8*)(KV + src);
            bf16x8 v8 = *(const bf16x8*)(KV + src + 1024);
            #pragma unroll
            for (int jj = 0; jj < 8; ++jj) {
                int d = c8 + jj;
                int off = d * 136 + ((r * 2) ^ (((d >> 3) & 7) << 4));
                *(bf16_t*)(vtb + off) = v8[jj];
            }
        }
        __syncthreads();

        f32x4 sacc[4] = {};
        #pragma unroll
        for (int kb = 0; kb < 4; ++kb)
            #pragma unroll
            for (int dc = 0; dc < 4; ++dc) {
                bf16x8 kf = *(const bf16x8*)(kl + (kb * 16 + l15) * 136 + dc * 32 + lg * 8);
                sacc[kb] = __builtin_amdgcn_mfma_f32_16x16x32_bf16(
                    kf, qf[dc], sacc[kb], 0, 0, 0);
            }

        float sv[16];
        float mt = -3.0e38f;
        #pragma unroll
        for (int kb = 0; kb < 4; ++kb)
            #pragma unroll
            for (int i = 0; i < 4; ++i) {
                float s = sacc[kb][i] * SCL;
                sv[kb * 4 + i] = s;
                mt = fmaxf(mt, s);
            }
        mt = fmaxf(mt, __shfl_xor(mt, 16));
        mt = fmaxf(mt, __shfl_xor(mt, 32));
        float mnew = fmaxf(mrun, mt);
        float alpha = exp2f((mrun - mnew) * L2E);

        float ts = 0.f;
        s16x4 pf[4];
        #pragma unroll
        for (int kb = 0; kb < 4; ++kb)
            #pragma unroll
            for (int i = 0; i < 4; ++i) {
                float p = exp2f((sv[kb * 4 + i] - mnew) * L2E);
                ts += p;
                pf[kb][i] = (short)__builtin_bit_cast(unsigned short, (bf16_t)p);
            }
        ts += __shfl_xor(ts, 16);
        ts += __shfl_xor(ts, 32);
        lrun = lrun * alpha + ts;
        mrun = mnew;

        #pragma unroll
        for (int i = 0; i < 4; ++i) {
            float ai = __shfl(alpha, lg * 4 + i);
            #pragma unroll
            for (int db = 0; db < 8; ++db) o[db][i] *= ai;
        }

        #pragma unroll
        for (int kb = 0; kb < 4; ++kb)
            #pragma unroll
            for (int db = 0; db < 8; ++db) {
                int d = l15 + 16 * db;
                int key0 = kb * 16 + lg * 4;
                int off = d * 136 + ((key0 * 2) ^ (((d >> 3) & 7) << 4));
                s16x4 vf = *(const s16x4*)(vtb + off);
                o[db] = __builtin_amdgcn_mfma_f32_16x16x16bf16_1k(
                    pf[kb], vf, o[db], 0, 0, 0);
            }
    }

    #pragma unroll
    for (int i = 0; i < 4; ++i) {
        float li = __shfl(lrun, lg * 4 + i);
        float inv = 1.0f / li;
        int row = b * SEQ + qt * 64 + wid * 16 + lg * 4 + i;
        #pragma unroll
        for (int db = 0; db < 8; ++db) {
            int col = h * HDIM + l15 + 16 * db;
            O[(size_t)row * DMODEL + col] = (bf16_t)(o[db][i] * inv);
        }
    }
}

// ---------------------------------------------------------------------------
// Launch: convert to bf16 -> QKV GEMMs (KV merged, N=2048) -> RoPE -> attn
// -> out proj. Workspace (bf16): Qw 32M | KVw 16M | AO 32M | xb 32M |
// wqb 32M | wkvb 16M | wob 32M  = 192 MiB.
// ---------------------------------------------------------------------------
extern "C" void kernel_launch(void* const* d_in, const int* in_sizes, int n_in,
                              void* d_out, int out_size, void* d_ws, size_t ws_size,
                              hipStream_t stream)
{
    const float* x  = (const float*)d_in[0];
    const float* wq = (const float*)d_in[1];
    const float* wk = (const float*)d_in[2];
    const float* wv = (const float*)d_in[3];
    const float* wo = (const float*)d_in[4];
    const float* fc = (const float*)d_in[5];
    const float* fs = (const float*)d_in[6];

    const size_t T = (size_t)4096;
    bf16_t* Qw   = (bf16_t*)d_ws;            // [4096][4096]
    bf16_t* KVw  = Qw   + T * 4096;          // [4096][2048]  (K | V)
    bf16_t* AO   = KVw  + T * 2048;          // [4096][4096]
    bf16_t* xb   = AO   + T * 4096;          // [4096][4096]
    bf16_t* wqb  = xb   + T * 4096;          // [4096][4096]
    bf16_t* wkvb = wqb  + T * 4096;          // [2048][4096]  (wk ; wv)
    bf16_t* wob  = wkvb + T * 2048;          // [4096][4096]

    f2b<<<8192, 256, 0, stream>>>(x,  xb,  4096 * 4096 / 8);
    f2b<<<8192, 256, 0, stream>>>(wq, wqb, 4096 * 4096 / 8);
    f2b<<<2048, 256, 0, stream>>>(wk, wkvb,                    1024 * 4096 / 8);
    f2b<<<2048, 256, 0, stream>>>(wv, wkvb + (size_t)1024 * 4096, 1024 * 4096 / 8);
    f2b<<<8192, 256, 0, stream>>>(wo, wob, 4096 * 4096 / 8);

    gemm_bt<false><<<1024, 256, 0, stream>>>(xb, wqb,  Qw,  4096, 4096, 4096, 32);
    gemm_bt<false><<<512,  256, 0, stream>>>(xb, wkvb, KVw, 4096, 2048, 4096, 16);

    rope_kernel<<<8192, 256, 0, stream>>>(Qw,  fc, fs, NHQ,  4096);
    rope_kernel<<<2048, 256, 0, stream>>>(KVw, fc, fs, NHKV, 2048);

    attn_kernel<<<2048, 256, 0, stream>>>(Qw, KVw, AO);

    gemm_bt<true><<<1024, 256, 0, stream>>>(AO, wob, d_out, 4096, 4096, 4096, 32);
}

// Round 3
// 610.102 us; speedup vs baseline: 1.7878x; 1.1355x over previous
//
#include <hip/hip_runtime.h>

typedef __bf16 bf16_t;
typedef __bf16 bf16x8 __attribute__((ext_vector_type(8)));
typedef __bf16 bf16x4 __attribute__((ext_vector_type(4)));
typedef float  f32x4  __attribute__((ext_vector_type(4)));
typedef short  s16x4  __attribute__((ext_vector_type(4)));

#define SEQ    1024
#define DMODEL 4096
#define NHQ    32
#define NHKV   8
#define HDIM   128

// async global->LDS, 16B per lane; LDS dest must be linear (base + lane*16)
#define GLOAD_LDS16(g, l)                                                  \
    __builtin_amdgcn_global_load_lds(                                      \
        (const __attribute__((address_space(1))) unsigned int*)(g),        \
        (__attribute__((address_space(3))) unsigned int*)(l), 16, 0, 0)

// ---------------------------------------------------------------------------
// fp32 -> bf16 convert, 8 elems/thread
// ---------------------------------------------------------------------------
__global__ __launch_bounds__(256)
void f2b(const float* __restrict__ in, bf16_t* __restrict__ out, int n8)
{
    int i = blockIdx.x * 256 + threadIdx.x;
    if (i >= n8) return;
    const float4* p = (const float4*)in + 2 * (size_t)i;
    float4 a = p[0], b = p[1];
    bf16x8 o;
    o[0] = (bf16_t)a.x; o[1] = (bf16_t)a.y; o[2] = (bf16_t)a.z; o[3] = (bf16_t)a.w;
    o[4] = (bf16_t)b.x; o[5] = (bf16_t)b.y; o[6] = (bf16_t)b.z; o[7] = (bf16_t)b.w;
    *((bf16x8*)out + i) = o;
}

// ---------------------------------------------------------------------------
// GEMM: C[M][N] = A[M][K] * B[N][K]^T, bf16 in.
// MODE 0: bf16 C (stride N). MODE 1: f32 C (stride N).
// MODE 2: KV split -- cols <1024 go to K buffer [M][1024] (bf16, normal);
//         cols >=1024 go TRANSPOSED to Vt[(col-1024)][tok] (stride M=4096),
//         as contiguous bf16x4 stores (D-frag rows are consecutive).
// m97 structure: 128x128 tile, BK=32, global_load_lds w=16, 2-barrier loop,
// XCD swizzle (grids % 8 == 0).
// ---------------------------------------------------------------------------
template<int MODE>
__global__ __launch_bounds__(256, 4)
void gemm_bt(const bf16_t* __restrict__ A, const bf16_t* __restrict__ B,
             void* __restrict__ Cv, bf16_t* __restrict__ Vt,
             int M, int N, int K, int nbn)
{
    __shared__ __align__(16) bf16_t lA[128 * 32];
    __shared__ __align__(16) bf16_t lB[128 * 32];

    const int nwg = gridDim.x;
    const int bid0 = blockIdx.x;
    const int bid = (bid0 & 7) * (nwg >> 3) + (bid0 >> 3);   // XCD swizzle
    const int bm = bid / nbn, bn = bid % nbn;
    const int t = threadIdx.x;
    const int lane = t & 63, wid = t >> 6;
    const int wrow = (wid >> 1) * 64, wcol = (wid & 1) * 64;
    const int l15 = lane & 15, lg = lane >> 4;
    const int m0 = bm * 128, n0 = bn * 128;

    const int r0 = t >> 2, pos0 = (t & 3) * 8;
    const int r1 = r0 + 64;

    const bf16_t* Ar0 = A + (size_t)(m0 + r0) * K + pos0;
    const bf16_t* Ar1 = A + (size_t)(m0 + r1) * K + pos0;
    const bf16_t* Br0 = B + (size_t)(n0 + r0) * K + pos0;
    const bf16_t* Br1 = B + (size_t)(n0 + r1) * K + pos0;

    f32x4 acc[4][4] = {};

    for (int k0 = 0; k0 < K; k0 += 32) {
        __syncthreads();
        GLOAD_LDS16(Ar0 + k0, lA + t * 8);
        GLOAD_LDS16(Ar1 + k0, lA + (t + 256) * 8);
        GLOAD_LDS16(Br0 + k0, lB + t * 8);
        GLOAD_LDS16(Br1 + k0, lB + (t + 256) * 8);
        __syncthreads();

        bf16x8 af[4], bfr[4];
        #pragma unroll
        for (int m = 0; m < 4; ++m)
            af[m] = *(const bf16x8*)(lA + (wrow + m * 16 + l15) * 32 + lg * 8);
        #pragma unroll
        for (int n = 0; n < 4; ++n)
            bfr[n] = *(const bf16x8*)(lB + (wcol + n * 16 + l15) * 32 + lg * 8);
        #pragma unroll
        for (int m = 0; m < 4; ++m)
            #pragma unroll
            for (int n = 0; n < 4; ++n)
                acc[m][n] = __builtin_amdgcn_mfma_f32_16x16x32_bf16(
                    af[m], bfr[n], acc[m][n], 0, 0, 0);
    }

    // D layout: col = lane&15, row = (lane>>4)*4 + i
    #pragma unroll
    for (int m = 0; m < 4; ++m) {
        #pragma unroll
        for (int n = 0; n < 4; ++n) {
            int col  = n0 + wcol + n * 16 + l15;
            int row0 = m0 + wrow + m * 16 + lg * 4;
            if constexpr (MODE == 0) {
                #pragma unroll
                for (int i = 0; i < 4; ++i)
                    ((bf16_t*)Cv)[(size_t)(row0 + i) * N + col] = (bf16_t)acc[m][n][i];
            } else if constexpr (MODE == 1) {
                #pragma unroll
                for (int i = 0; i < 4; ++i)
                    ((float*)Cv)[(size_t)(row0 + i) * N + col] = acc[m][n][i];
            } else {
                if (col < 1024) {
                    #pragma unroll
                    for (int i = 0; i < 4; ++i)
                        ((bf16_t*)Cv)[(size_t)(row0 + i) * 1024 + col] = (bf16_t)acc[m][n][i];
                } else {
                    bf16x4 pk;
                    #pragma unroll
                    for (int i = 0; i < 4; ++i) pk[i] = (bf16_t)acc[m][n][i];
                    *(bf16x4*)(Vt + (size_t)(col - 1024) * 4096 + row0) = pk;
                }
            }
        }
    }
}

// ---------------------------------------------------------------------------
// RoPE (interleaved pairs), in-place on bf16, 8 elems (4 pairs) per thread.
// ---------------------------------------------------------------------------
__global__ __launch_bounds__(256)
void rope_kernel(bf16_t* __restrict__ X, const float* __restrict__ fc,
                 const float* __restrict__ fs, int nheads, int rowstride)
{
    int idx = blockIdx.x * 256 + threadIdx.x;
    int j4 = idx & 15;
    int rest = idx >> 4;
    int h = rest % nheads;
    int tok = rest / nheads;
    int s = tok & (SEQ - 1);
    bf16_t* p = X + (size_t)tok * rowstride + h * HDIM + j4 * 8;
    bf16x8 v = *(const bf16x8*)p;
    float4 c  = *(const float4*)(fc + s * 64 + j4 * 4);
    float4 sn = *(const float4*)(fs + s * 64 + j4 * 4);
    bf16x8 o;
    o[0] = (bf16_t)((float)v[0] * c.x - (float)v[1] * sn.x);
    o[1] = (bf16_t)((float)v[0] * sn.x + (float)v[1] * c.x);
    o[2] = (bf16_t)((float)v[2] * c.y - (float)v[3] * sn.y);
    o[3] = (bf16_t)((float)v[2] * sn.y + (float)v[3] * c.y);
    o[4] = (bf16_t)((float)v[4] * c.z - (float)v[5] * sn.z);
    o[5] = (bf16_t)((float)v[4] * sn.z + (float)v[5] * c.z);
    o[6] = (bf16_t)((float)v[6] * c.w - (float)v[7] * sn.w);
    o[7] = (bf16_t)((float)v[6] * sn.w + (float)v[7] * c.w);
    *(bf16x8*)p = o;
}

// ---------------------------------------------------------------------------
// Flash attention (non-causal), GQA 4:1.
// K: [tok][kv*128+d] row-major (stride 1024). Vt: [kv*128+d][tok] (stride 4096).
// Both tiles staged via global_load_lds w=16 into LINEAR LDS with
// pre-swizzled SOURCE (XOR ((row&7)<<4)); reads apply the same XOR ->
// conflict-free ds_read_b128 (QK^T) and ds_read_b64 (PV). No transposes.
// Swapped QK^T, in-register softmax, P^T regs feed 16x16x16 MFMA as A.
// 32KB LDS, 4 blocks/CU.
// ---------------------------------------------------------------------------
__global__ __launch_bounds__(256, 4)
void attn_kernel(const bf16_t* __restrict__ Q, const bf16_t* __restrict__ Kg,
                 const bf16_t* __restrict__ Vtg, bf16_t* __restrict__ O)
{
    __shared__ __align__(16) char klds[64 * 256];    // K tile [key][d], swizzled
    __shared__ __align__(16) char vlds[128 * 128];   // V^T tile [d][key], swizzled

    const int nwg = gridDim.x;
    const int bid0 = blockIdx.x;
    const int blk = (bid0 & 7) * (nwg >> 3) + (bid0 >> 3);   // XCD swizzle
    const int qt = blk & 15;
    const int bh = blk >> 4;
    const int b = bh >> 5, h = bh & 31, kv = h >> 2;
    const int t = threadIdx.x, lane = t & 63, wid = t >> 6;
    const int l15 = lane & 15, lg = lane >> 4;
    const int swzk = (l15 & 7) << 4;

    const float SCL = 0.08838834764831845f;   // 1/sqrt(128)
    const float L2E = 1.4426950408889634f;

    const int qrow = qt * 64 + wid * 16 + l15;
    const size_t qbase = (size_t)(b * SEQ + qrow) * DMODEL + h * HDIM;
    bf16x8 qf[4];
    #pragma unroll
    for (int dc = 0; dc < 4; ++dc)
        qf[dc] = *(const bf16x8*)(Q + qbase + dc * 32 + lg * 8);

    // staging bases (byte offsets)
    const char* kgb = (const char*)Kg + ((size_t)(b * SEQ) * 1024 + kv * HDIM) * 2;
    const char* vgb = (const char*)Vtg + ((size_t)(kv * HDIM) * 4096 + b * SEQ) * 2;

    f32x4 o[8] = {};
    float mrun = -3.0e38f, lrun = 0.f;

    for (int kt = 0; kt < 16; ++kt) {
        __syncthreads();
        #pragma unroll
        for (int i = 0; i < 4; ++i) {
            int idx = t + 256 * i;
            {   // K tile: row r (key), 16 chunks of 16B per row
                int r = idx >> 4, cb = (idx & 15) << 4;
                const char* src = kgb + (size_t)(kt * 64 + r) * 2048
                                      + (cb ^ ((r & 7) << 4));
                GLOAD_LDS16(src, klds + idx * 16);
            }
            {   // V^T tile: row d, 8 chunks of 16B per row
                int d = idx >> 3, cb = (idx & 7) << 4;
                const char* src = vgb + (size_t)d * 8192 + kt * 128
                                      + (cb ^ ((d & 7) << 4));
                GLOAD_LDS16(src, vlds + idx * 16);
            }
        }
        __syncthreads();

        // ---- QK^T -> S^T[key][q] ----
        f32x4 sacc[4] = {};
        #pragma unroll
        for (int kb = 0; kb < 4; ++kb) {
            const char* krow = klds + (kb * 16 + l15) * 256;
            #pragma unroll
            for (int dc = 0; dc < 4; ++dc) {
                bf16x8 kf = *(const bf16x8*)(krow + ((dc * 64 + lg * 16) ^ swzk));
                sacc[kb] = __builtin_amdgcn_mfma_f32_16x16x32_bf16(
                    kf, qf[dc], sacc[kb], 0, 0, 0);
            }
        }

        // ---- online softmax (per lane: q = l15) ----
        float sv[16];
        float mt = -3.0e38f;
        #pragma unroll
        for (int kb = 0; kb < 4; ++kb)
            #pragma unroll
            for (int i = 0; i < 4; ++i) {
                float s = sacc[kb][i] * SCL;
                sv[kb * 4 + i] = s;
                mt = fmaxf(mt, s);
            }
        mt = fmaxf(mt, __shfl_xor(mt, 16));
        mt = fmaxf(mt, __shfl_xor(mt, 32));
        float mnew = fmaxf(mrun, mt);
        float alpha = exp2f((mrun - mnew) * L2E);

        float ts = 0.f;
        s16x4 pf[4];
        #pragma unroll
        for (int kb = 0; kb < 4; ++kb)
            #pragma unroll
            for (int i = 0; i < 4; ++i) {
                float p = exp2f((sv[kb * 4 + i] - mnew) * L2E);
                ts += p;
                pf[kb][i] = (short)__builtin_bit_cast(unsigned short, (bf16_t)p);
            }
        ts += __shfl_xor(ts, 16);
        ts += __shfl_xor(ts, 32);
        lrun = lrun * alpha + ts;
        mrun = mnew;

        #pragma unroll
        for (int i = 0; i < 4; ++i) {
            float ai = __shfl(alpha, lg * 4 + i);
            #pragma unroll
            for (int db = 0; db < 8; ++db) o[db][i] *= ai;
        }

        // ---- PV: vf[j] = V[key0+j][d] read from V^T rows ----
        #pragma unroll
        for (int kb = 0; kb < 4; ++kb)
            #pragma unroll
            for (int db = 0; db < 8; ++db) {
                int d = l15 + 16 * db;               // d&7 == l15&7
                const char* va = vlds + d * 128 + ((kb * 32 + lg * 8) ^ swzk);
                s16x4 vf = *(const s16x4*)va;
                o[db] = __builtin_amdgcn_mfma_f32_16x16x16bf16_1k(
                    pf[kb], vf, o[db], 0, 0, 0);
            }
    }

    #pragma unroll
    for (int i = 0; i < 4; ++i) {
        float li = __shfl(lrun, lg * 4 + i);
        float inv = 1.0f / li;
        int row = b * SEQ + qt * 64 + wid * 16 + lg * 4 + i;
        #pragma unroll
        for (int db = 0; db < 8; ++db) {
            int col = h * HDIM + l15 + 16 * db;
            O[(size_t)row * DMODEL + col] = (bf16_t)(o[db][i] * inv);
        }
    }
}

// ---------------------------------------------------------------------------
// Launch. Workspace (bf16): Qw 32M | Kw2 8M | Vt 8M | AO 32M | xb 32M |
// wqb 32M | wkvb 16M | wob 32M = 192 MiB.
// ---------------------------------------------------------------------------
extern "C" void kernel_launch(void* const* d_in, const int* in_sizes, int n_in,
                              void* d_out, int out_size, void* d_ws, size_t ws_size,
                              hipStream_t stream)
{
    const float* x  = (const float*)d_in[0];
    const float* wq = (const float*)d_in[1];
    const float* wk = (const float*)d_in[2];
    const float* wv = (const float*)d_in[3];
    const float* wo = (const float*)d_in[4];
    const float* fc = (const float*)d_in[5];
    const float* fs = (const float*)d_in[6];

    const size_t T = (size_t)4096;
    bf16_t* Qw   = (bf16_t*)d_ws;            // [4096][4096]
    bf16_t* Kw2  = Qw   + T * 4096;          // [4096][1024]
    bf16_t* Vt   = Kw2  + T * 1024;          // [1024(kv*128+d)][4096 tok]
    bf16_t* AO   = Vt   + T * 1024;          // [4096][4096]
    bf16_t* xb   = AO   + T * 4096;          // [4096][4096]
    bf16_t* wqb  = xb   + T * 4096;          // [4096][4096]
    bf16_t* wkvb = wqb  + T * 4096;          // [2048][4096]  (wk ; wv)
    bf16_t* wob  = wkvb + T * 2048;          // [4096][4096]

    f2b<<<8192, 256, 0, stream>>>(x,  xb,  4096 * 4096 / 8);
    f2b<<<8192, 256, 0, stream>>>(wq, wqb, 4096 * 4096 / 8);
    f2b<<<2048, 256, 0, stream>>>(wk, wkvb,                       1024 * 4096 / 8);
    f2b<<<2048, 256, 0, stream>>>(wv, wkvb + (size_t)1024 * 4096, 1024 * 4096 / 8);
    f2b<<<8192, 256, 0, stream>>>(wo, wob, 4096 * 4096 / 8);

    gemm_bt<0><<<1024, 256, 0, stream>>>(xb, wqb,  Qw,  nullptr, 4096, 4096, 4096, 32);
    gemm_bt<2><<<512,  256, 0, stream>>>(xb, wkvb, Kw2, Vt,      4096, 2048, 4096, 16);

    rope_kernel<<<8192, 256, 0, stream>>>(Qw,  fc, fs, NHQ,  4096);
    rope_kernel<<<2048, 256, 0, stream>>>(Kw2, fc, fs, NHKV, 1024);

    attn_kernel<<<2048, 256, 0, stream>>>(Qw, Kw2, Vt, AO);

    gemm_bt<1><<<1024, 256, 0, stream>>>(AO, wob, d_out, nullptr, 4096, 4096, 4096, 32);
}

// Round 4
// 591.349 us; speedup vs baseline: 1.8445x; 1.0317x over previous
//
#include <hip/hip_runtime.h>

typedef __bf16 bf16_t;
typedef __bf16 bf16x8 __attribute__((ext_vector_type(8)));
typedef __bf16 bf16x4 __attribute__((ext_vector_type(4)));
typedef float  f32x4  __attribute__((ext_vector_type(4)));
typedef short  s16x4  __attribute__((ext_vector_type(4)));

#define SEQ    1024
#define DMODEL 4096
#define NHQ    32
#define NHKV   8
#define HDIM   128

// async global->LDS, 16B per lane; LDS dest must be linear (base + lane*16)
#define GLOAD_LDS16(g, l)                                                  \
    __builtin_amdgcn_global_load_lds(                                      \
        (const __attribute__((address_space(1))) unsigned int*)(g),        \
        (__attribute__((address_space(3))) unsigned int*)(l), 16, 0, 0)

// ---------------------------------------------------------------------------
// fp32 -> bf16 convert, 8 elems/thread
// ---------------------------------------------------------------------------
__global__ __launch_bounds__(256)
void f2b(const float* __restrict__ in, bf16_t* __restrict__ out, int n8)
{
    int i = blockIdx.x * 256 + threadIdx.x;
    if (i >= n8) return;
    const float4* p = (const float4*)in + 2 * (size_t)i;
    float4 a = p[0], b = p[1];
    bf16x8 o;
    o[0] = (bf16_t)a.x; o[1] = (bf16_t)a.y; o[2] = (bf16_t)a.z; o[3] = (bf16_t)a.w;
    o[4] = (bf16_t)b.x; o[5] = (bf16_t)b.y; o[6] = (bf16_t)b.z; o[7] = (bf16_t)b.w;
    *((bf16x8*)out + i) = o;
}

// ---------------------------------------------------------------------------
// 256x256 8-wave deep-pipelined GEMM: C[M][N] = A[M][K] * B[N][K]^T (bf16 in).
// Quad-buffered BK=32 variant of the 8-phase template: tile t stages tile t+2
// into buf (t+2)&3 -- the staged buffer is NEVER the one being read, so
// write-after-read safety is structural (reads drained by lgkmcnt(0) before
// the phase's closing barrier; overwriting loads issued >=2 tiles later).
// Counted vmcnt(4) at each tile end (never 0 in the loop) keeps 1 tile of
// loads in flight across barriers. Per phase: {ds_read frags | stage 2x
// global_load_lds | barrier | lgkmcnt(0) | setprio(1) 16xMFMA setprio(0) |
// barrier}. LDS swizzle: chunk ^= (row>>1)&3 (16B chunks, 64B rows) -> frag
// reads 2-way only; staged via pre-swizzled global source (linear LDS dest).
// ---------------------------------------------------------------------------
#define STAGE_A(b, ks)  do {                                               \
    const char* as_ = Ab + (size_t)srow * Krb + (ks) + scol0;              \
    GLOAD_LDS16(as_,             ldsA[b] + t * 16);                        \
    GLOAD_LDS16(as_ + 128 * Krb, ldsA[b] + 8192 + t * 16);                 \
} while (0)
#define STAGE_B(b, ks)  do {                                               \
    const char* bs_ = Bb + (size_t)srow * Krb + (ks) + scol0;              \
    GLOAD_LDS16(bs_,             ldsB[b] + t * 16);                        \
    GLOAD_LDS16(bs_ + 128 * Krb, ldsB[b] + 8192 + t * 16);                 \
} while (0)
#define LDS_AT(buf, row, lg_) \
    (*(const bf16x8*)((buf) + (row) * 64 + (((lg_) * 16) ^ ((((row) >> 1) & 3) << 4))))

#define TILE(bufi, tno)  do {                                              \
    const int ks2_ = ((tno) + 2 < NT) ? ((tno) + 2) * 64 : (tno) * 64;     \
    /* ---- phase alpha: A frags + B frags(n=0,1), stage A of t+2 ---- */  \
    bf16x8 af[8], bfr0, bfr1;                                              \
    _Pragma("unroll")                                                      \
    for (int m = 0; m < 8; ++m) {                                          \
        int row = wm * 128 + m * 16 + l15;                                 \
        af[m] = LDS_AT(ldsA[bufi], row, lg);                               \
    }                                                                      \
    { int rb = wn * 64 + l15;      bfr0 = LDS_AT(ldsB[bufi], rb, lg); }    \
    { int rb = wn * 64 + 16 + l15; bfr1 = LDS_AT(ldsB[bufi], rb, lg); }    \
    STAGE_A(((tno) + 2) & 3, ks2_);                                        \
    __builtin_amdgcn_sched_barrier(0);                                     \
    __builtin_amdgcn_s_barrier();                                          \
    asm volatile("s_waitcnt lgkmcnt(0)" ::: "memory");                     \
    __builtin_amdgcn_sched_barrier(0);                                     \
    __builtin_amdgcn_s_setprio(1);                                         \
    _Pragma("unroll")                                                      \
    for (int m = 0; m < 8; ++m) {                                          \
        acc[m][0] = __builtin_amdgcn_mfma_f32_16x16x32_bf16(af[m], bfr0, acc[m][0], 0, 0, 0); \
        acc[m][1] = __builtin_amdgcn_mfma_f32_16x16x32_bf16(af[m], bfr1, acc[m][1], 0, 0, 0); \
    }                                                                      \
    __builtin_amdgcn_s_setprio(0);                                         \
    __builtin_amdgcn_sched_barrier(0);                                     \
    __builtin_amdgcn_s_barrier();                                          \
    /* ---- phase beta: B frags(n=2,3), reuse af, stage B of t+2 ---- */   \
    { int rb = wn * 64 + 32 + l15; bfr0 = LDS_AT(ldsB[bufi], rb, lg); }    \
    { int rb = wn * 64 + 48 + l15; bfr1 = LDS_AT(ldsB[bufi], rb, lg); }    \
    STAGE_B(((tno) + 2) & 3, ks2_);                                        \
    __builtin_amdgcn_sched_barrier(0);                                     \
    __builtin_amdgcn_s_barrier();                                          \
    asm volatile("s_waitcnt lgkmcnt(0)" ::: "memory");                     \
    __builtin_amdgcn_sched_barrier(0);                                     \
    __builtin_amdgcn_s_setprio(1);                                         \
    _Pragma("unroll")                                                      \
    for (int m = 0; m < 8; ++m) {                                          \
        acc[m][2] = __builtin_amdgcn_mfma_f32_16x16x32_bf16(af[m], bfr0, acc[m][2], 0, 0, 0); \
        acc[m][3] = __builtin_amdgcn_mfma_f32_16x16x32_bf16(af[m], bfr1, acc[m][3], 0, 0, 0); \
    }                                                                      \
    __builtin_amdgcn_s_setprio(0);                                         \
    asm volatile("s_waitcnt vmcnt(4)" ::: "memory");                       \
    __builtin_amdgcn_sched_barrier(0);                                     \
    __builtin_amdgcn_s_barrier();                                          \
} while (0)

template<bool OUT_F32>
__global__ __launch_bounds__(512, 2)
void gemm256(const bf16_t* __restrict__ A, const bf16_t* __restrict__ B,
             void* __restrict__ Cv, int M, int N, int K, int nbn)
{
    __shared__ __align__(16) char ldsA[4][16384];   // 4 bufs x 256 rows x 64B
    __shared__ __align__(16) char ldsB[4][16384];

    const int nwg = gridDim.x;
    const int bid0 = blockIdx.x;
    const int bid = (bid0 & 7) * (nwg >> 3) + (bid0 >> 3);   // XCD swizzle
    const int bm = bid / nbn, bn = bid % nbn;
    const int t = threadIdx.x;
    const int lane = t & 63, wid = t >> 6;
    const int wm = wid >> 2, wn = wid & 3;          // 2M x 4N waves
    const int l15 = lane & 15, lg = lane >> 4;
    const int m0 = bm * 256, n0 = bn * 256;

    // staging map: per inst, 512 thr x 16B = 128 rows x 64B; t -> row t>>2, chunk t&3
    const int srow = t >> 2;
    const int scol0 = (((t & 3) ^ ((srow >> 1) & 3)) << 4);  // pre-swizzled src col
    const int Krb = K * 2;                                   // row bytes
    const char* Ab = (const char*)A + (size_t)m0 * Krb;
    const char* Bb = (const char*)B + (size_t)n0 * Krb;

    const int NT = K >> 5;                                   // K-tiles of 32
    f32x4 acc[8][4] = {};

    // prologue: tiles 0,1 staged; tile 0 landed, tile 1 in flight (4 loads)
    STAGE_A(0, 0);  STAGE_B(0, 0);
    STAGE_A(1, 64); STAGE_B(1, 64);
    asm volatile("s_waitcnt vmcnt(4)" ::: "memory");
    __builtin_amdgcn_sched_barrier(0);
    __builtin_amdgcn_s_barrier();

    for (int tt = 0; tt < NT; tt += 4) {
        TILE(0, tt + 0);
        TILE(1, tt + 1);
        TILE(2, tt + 2);
        TILE(3, tt + 3);
    }

    // epilogue: D col = lane&15, row = (lane>>4)*4 + i
    #pragma unroll
    for (int m = 0; m < 8; ++m) {
        int row0 = m0 + wm * 128 + m * 16 + lg * 4;
        #pragma unroll
        for (int n = 0; n < 4; ++n) {
            int col = n0 + wn * 64 + n * 16 + l15;
            #pragma unroll
            for (int i = 0; i < 4; ++i) {
                if constexpr (OUT_F32)
                    ((float*)Cv)[(size_t)(row0 + i) * N + col] = acc[m][n][i];
                else
                    ((bf16_t*)Cv)[(size_t)(row0 + i) * N + col] = (bf16_t)acc[m][n][i];
            }
        }
    }
}
#undef TILE
#undef LDS_AT
#undef STAGE_A
#undef STAGE_B

// ---------------------------------------------------------------------------
// 128x128 m97-structure GEMM, kept for the KV projection (N=2048 -> 512
// blocks; a 256 tile would leave half the CUs idle). MODE 2 epilogue splits
// cols <1024 to K buffer, cols >=1024 transposed to Vt[(col-1024)][tok].
// ---------------------------------------------------------------------------
template<int MODE>
__global__ __launch_bounds__(256, 4)
void gemm_bt(const bf16_t* __restrict__ A, const bf16_t* __restrict__ B,
             void* __restrict__ Cv, bf16_t* __restrict__ Vt,
             int M, int N, int K, int nbn)
{
    __shared__ __align__(16) bf16_t lA[128 * 32];
    __shared__ __align__(16) bf16_t lB[128 * 32];

    const int nwg = gridDim.x;
    const int bid0 = blockIdx.x;
    const int bid = (bid0 & 7) * (nwg >> 3) + (bid0 >> 3);
    const int bm = bid / nbn, bn = bid % nbn;
    const int t = threadIdx.x;
    const int lane = t & 63, wid = t >> 6;
    const int wrow = (wid >> 1) * 64, wcol = (wid & 1) * 64;
    const int l15 = lane & 15, lg = lane >> 4;
    const int m0 = bm * 128, n0 = bn * 128;

    const int r0 = t >> 2, pos0 = (t & 3) * 8;
    const int r1 = r0 + 64;

    const bf16_t* Ar0 = A + (size_t)(m0 + r0) * K + pos0;
    const bf16_t* Ar1 = A + (size_t)(m0 + r1) * K + pos0;
    const bf16_t* Br0 = B + (size_t)(n0 + r0) * K + pos0;
    const bf16_t* Br1 = B + (size_t)(n0 + r1) * K + pos0;

    f32x4 acc[4][4] = {};

    for (int k0 = 0; k0 < K; k0 += 32) {
        __syncthreads();
        GLOAD_LDS16(Ar0 + k0, lA + t * 8);
        GLOAD_LDS16(Ar1 + k0, lA + (t + 256) * 8);
        GLOAD_LDS16(Br0 + k0, lB + t * 8);
        GLOAD_LDS16(Br1 + k0, lB + (t + 256) * 8);
        __syncthreads();

        bf16x8 af[4], bfr[4];
        #pragma unroll
        for (int m = 0; m < 4; ++m)
            af[m] = *(const bf16x8*)(lA + (wrow + m * 16 + l15) * 32 + lg * 8);
        #pragma unroll
        for (int n = 0; n < 4; ++n)
            bfr[n] = *(const bf16x8*)(lB + (wcol + n * 16 + l15) * 32 + lg * 8);
        #pragma unroll
        for (int m = 0; m < 4; ++m)
            #pragma unroll
            for (int n = 0; n < 4; ++n)
                acc[m][n] = __builtin_amdgcn_mfma_f32_16x16x32_bf16(
                    af[m], bfr[n], acc[m][n], 0, 0, 0);
    }

    #pragma unroll
    for (int m = 0; m < 4; ++m) {
        #pragma unroll
        for (int n = 0; n < 4; ++n) {
            int col  = n0 + wcol + n * 16 + l15;
            int row0 = m0 + wrow + m * 16 + lg * 4;
            if constexpr (MODE == 0) {
                #pragma unroll
                for (int i = 0; i < 4; ++i)
                    ((bf16_t*)Cv)[(size_t)(row0 + i) * N + col] = (bf16_t)acc[m][n][i];
            } else if constexpr (MODE == 1) {
                #pragma unroll
                for (int i = 0; i < 4; ++i)
                    ((float*)Cv)[(size_t)(row0 + i) * N + col] = acc[m][n][i];
            } else {
                if (col < 1024) {
                    #pragma unroll
                    for (int i = 0; i < 4; ++i)
                        ((bf16_t*)Cv)[(size_t)(row0 + i) * 1024 + col] = (bf16_t)acc[m][n][i];
                } else {
                    bf16x4 pk;
                    #pragma unroll
                    for (int i = 0; i < 4; ++i) pk[i] = (bf16_t)acc[m][n][i];
                    *(bf16x4*)(Vt + (size_t)(col - 1024) * 4096 + row0) = pk;
                }
            }
        }
    }
}

// ---------------------------------------------------------------------------
// RoPE (interleaved pairs), in-place on bf16, 8 elems (4 pairs) per thread.
// ---------------------------------------------------------------------------
__global__ __launch_bounds__(256)
void rope_kernel(bf16_t* __restrict__ X, const float* __restrict__ fc,
                 const float* __restrict__ fs, int nheads, int rowstride)
{
    int idx = blockIdx.x * 256 + threadIdx.x;
    int j4 = idx & 15;
    int rest = idx >> 4;
    int h = rest % nheads;
    int tok = rest / nheads;
    int s = tok & (SEQ - 1);
    bf16_t* p = X + (size_t)tok * rowstride + h * HDIM + j4 * 8;
    bf16x8 v = *(const bf16x8*)p;
    float4 c  = *(const float4*)(fc + s * 64 + j4 * 4);
    float4 sn = *(const float4*)(fs + s * 64 + j4 * 4);
    bf16x8 o;
    o[0] = (bf16_t)((float)v[0] * c.x - (float)v[1] * sn.x);
    o[1] = (bf16_t)((float)v[0] * sn.x + (float)v[1] * c.x);
    o[2] = (bf16_t)((float)v[2] * c.y - (float)v[3] * sn.y);
    o[3] = (bf16_t)((float)v[2] * sn.y + (float)v[3] * c.y);
    o[4] = (bf16_t)((float)v[4] * c.z - (float)v[5] * sn.z);
    o[5] = (bf16_t)((float)v[4] * sn.z + (float)v[5] * c.z);
    o[6] = (bf16_t)((float)v[6] * c.w - (float)v[7] * sn.w);
    o[7] = (bf16_t)((float)v[6] * sn.w + (float)v[7] * c.w);
    *(bf16x8*)p = o;
}

// ---------------------------------------------------------------------------
// Flash attention (non-causal), GQA 4:1.
// K: [tok][kv*128+d] (stride 1024). Vt: [kv*128+d][tok] (stride 4096).
// global_load_lds staging with pre-swizzled source; swapped QK^T; in-register
// softmax; P^T regs feed 16x16x16 MFMA. 32KB LDS, 4 blocks/CU.
// ---------------------------------------------------------------------------
__global__ __launch_bounds__(256, 4)
void attn_kernel(const bf16_t* __restrict__ Q, const bf16_t* __restrict__ Kg,
                 const bf16_t* __restrict__ Vtg, bf16_t* __restrict__ O)
{
    __shared__ __align__(16) char klds[64 * 256];    // K tile [key][d], swizzled
    __shared__ __align__(16) char vlds[128 * 128];   // V^T tile [d][key], swizzled

    const int nwg = gridDim.x;
    const int bid0 = blockIdx.x;
    const int blk = (bid0 & 7) * (nwg >> 3) + (bid0 >> 3);
    const int qt = blk & 15;
    const int bh = blk >> 4;
    const int b = bh >> 5, h = bh & 31, kv = h >> 2;
    const int t = threadIdx.x, lane = t & 63, wid = t >> 6;
    const int l15 = lane & 15, lg = lane >> 4;
    const int swzk = (l15 & 7) << 4;

    const float SCL = 0.08838834764831845f;
    const float L2E = 1.4426950408889634f;

    const int qrow = qt * 64 + wid * 16 + l15;
    const size_t qbase = (size_t)(b * SEQ + qrow) * DMODEL + h * HDIM;
    bf16x8 qf[4];
    #pragma unroll
    for (int dc = 0; dc < 4; ++dc)
        qf[dc] = *(const bf16x8*)(Q + qbase + dc * 32 + lg * 8);

    const char* kgb = (const char*)Kg + ((size_t)(b * SEQ) * 1024 + kv * HDIM) * 2;
    const char* vgb = (const char*)Vtg + ((size_t)(kv * HDIM) * 4096 + b * SEQ) * 2;

    f32x4 o[8] = {};
    float mrun = -3.0e38f, lrun = 0.f;

    for (int kt = 0; kt < 16; ++kt) {
        __syncthreads();
        #pragma unroll
        for (int i = 0; i < 4; ++i) {
            int idx = t + 256 * i;
            {
                int r = idx >> 4, cb = (idx & 15) << 4;
                const char* src = kgb + (size_t)(kt * 64 + r) * 2048
                                      + (cb ^ ((r & 7) << 4));
                GLOAD_LDS16(src, klds + idx * 16);
            }
            {
                int d = idx >> 3, cb = (idx & 7) << 4;
                const char* src = vgb + (size_t)d * 8192 + kt * 128
                                      + (cb ^ ((d & 7) << 4));
                GLOAD_LDS16(src, vlds + idx * 16);
            }
        }
        __syncthreads();

        f32x4 sacc[4] = {};
        #pragma unroll
        for (int kb = 0; kb < 4; ++kb) {
            const char* krow = klds + (kb * 16 + l15) * 256;
            #pragma unroll
            for (int dc = 0; dc < 4; ++dc) {
                bf16x8 kf = *(const bf16x8*)(krow + ((dc * 64 + lg * 16) ^ swzk));
                sacc[kb] = __builtin_amdgcn_mfma_f32_16x16x32_bf16(
                    kf, qf[dc], sacc[kb], 0, 0, 0);
            }
        }

        float sv[16];
        float mt = -3.0e38f;
        #pragma unroll
        for (int kb = 0; kb < 4; ++kb)
            #pragma unroll
            for (int i = 0; i < 4; ++i) {
                float s = sacc[kb][i] * SCL;
                sv[kb * 4 + i] = s;
                mt = fmaxf(mt, s);
            }
        mt = fmaxf(mt, __shfl_xor(mt, 16));
        mt = fmaxf(mt, __shfl_xor(mt, 32));
        float mnew = fmaxf(mrun, mt);
        float alpha = exp2f((mrun - mnew) * L2E);

        float ts = 0.f;
        s16x4 pf[4];
        #pragma unroll
        for (int kb = 0; kb < 4; ++kb)
            #pragma unroll
            for (int i = 0; i < 4; ++i) {
                float p = exp2f((sv[kb * 4 + i] - mnew) * L2E);
                ts += p;
                pf[kb][i] = (short)__builtin_bit_cast(unsigned short, (bf16_t)p);
            }
        ts += __shfl_xor(ts, 16);
        ts += __shfl_xor(ts, 32);
        lrun = lrun * alpha + ts;
        mrun = mnew;

        #pragma unroll
        for (int i = 0; i < 4; ++i) {
            float ai = __shfl(alpha, lg * 4 + i);
            #pragma unroll
            for (int db = 0; db < 8; ++db) o[db][i] *= ai;
        }

        #pragma unroll
        for (int kb = 0; kb < 4; ++kb)
            #pragma unroll
            for (int db = 0; db < 8; ++db) {
                int d = l15 + 16 * db;
                const char* va = vlds + d * 128 + ((kb * 32 + lg * 8) ^ swzk);
                s16x4 vf = *(const s16x4*)va;
                o[db] = __builtin_amdgcn_mfma_f32_16x16x16bf16_1k(
                    pf[kb], vf, o[db], 0, 0, 0);
            }
    }

    #pragma unroll
    for (int i = 0; i < 4; ++i) {
        float li = __shfl(lrun, lg * 4 + i);
        float inv = 1.0f / li;
        int row = b * SEQ + qt * 64 + wid * 16 + lg * 4 + i;
        #pragma unroll
        for (int db = 0; db < 8; ++db) {
            int col = h * HDIM + l15 + 16 * db;
            O[(size_t)row * DMODEL + col] = (bf16_t)(o[db][i] * inv);
        }
    }
}

// ---------------------------------------------------------------------------
// Launch. Workspace (bf16): Qw 32M | Kw2 8M | Vt 8M | AO 32M | xb 32M |
// wqb 32M | wkvb 16M | wob 32M = 192 MiB.
// ---------------------------------------------------------------------------
extern "C" void kernel_launch(void* const* d_in, const int* in_sizes, int n_in,
                              void* d_out, int out_size, void* d_ws, size_t ws_size,
                              hipStream_t stream)
{
    const float* x  = (const float*)d_in[0];
    const float* wq = (const float*)d_in[1];
    const float* wk = (const float*)d_in[2];
    const float* wv = (const float*)d_in[3];
    const float* wo = (const float*)d_in[4];
    const float* fc = (const float*)d_in[5];
    const float* fs = (const float*)d_in[6];

    const size_t T = (size_t)4096;
    bf16_t* Qw   = (bf16_t*)d_ws;            // [4096][4096]
    bf16_t* Kw2  = Qw   + T * 4096;          // [4096][1024]
    bf16_t* Vt   = Kw2  + T * 1024;          // [1024(kv*128+d)][4096 tok]
    bf16_t* AO   = Vt   + T * 1024;          // [4096][4096]
    bf16_t* xb   = AO   + T * 4096;          // [4096][4096]
    bf16_t* wqb  = xb   + T * 4096;          // [4096][4096]
    bf16_t* wkvb = wqb  + T * 4096;          // [2048][4096]  (wk ; wv)
    bf16_t* wob  = wkvb + T * 2048;          // [4096][4096]

    f2b<<<8192, 256, 0, stream>>>(x,  xb,  4096 * 4096 / 8);
    f2b<<<8192, 256, 0, stream>>>(wq, wqb, 4096 * 4096 / 8);
    f2b<<<2048, 256, 0, stream>>>(wk, wkvb,                       1024 * 4096 / 8);
    f2b<<<2048, 256, 0, stream>>>(wv, wkvb + (size_t)1024 * 4096, 1024 * 4096 / 8);
    f2b<<<8192, 256, 0, stream>>>(wo, wob, 4096 * 4096 / 8);

    gemm256<false><<<256, 512, 0, stream>>>(xb, wqb, Qw, 4096, 4096, 4096, 16);
    gemm_bt<2><<<512, 256, 0, stream>>>(xb, wkvb, Kw2, Vt, 4096, 2048, 4096, 16);

    rope_kernel<<<8192, 256, 0, stream>>>(Qw,  fc, fs, NHQ,  4096);
    rope_kernel<<<2048, 256, 0, stream>>>(Kw2, fc, fs, NHKV, 1024);

    attn_kernel<<<2048, 256, 0, stream>>>(Qw, Kw2, Vt, AO);

    gemm256<true><<<256, 512, 0, stream>>>(AO, wob, d_out, 4096, 4096, 4096, 16);
}

// Round 5
// 563.941 us; speedup vs baseline: 1.9342x; 1.0486x over previous
//
#include <hip/hip_runtime.h>

typedef __bf16 bf16_t;
typedef __bf16 bf16x8 __attribute__((ext_vector_type(8)));
typedef __bf16 bf16x4 __attribute__((ext_vector_type(4)));
typedef float  f32x4  __attribute__((ext_vector_type(4)));
typedef short  s16x4  __attribute__((ext_vector_type(4)));

#define SEQ    1024
#define DMODEL 4096
#define NHQ    32
#define NHKV   8
#define HDIM   128

// async global->LDS, 16B per lane; LDS dest must be linear (base + lane*16)
#define GLOAD_LDS16(g, l)                                                  \
    __builtin_amdgcn_global_load_lds(                                      \
        (const __attribute__((address_space(1))) unsigned int*)(g),        \
        (__attribute__((address_space(3))) unsigned int*)(l), 16, 0, 0)

// ---------------------------------------------------------------------------
// fp32 -> bf16 convert, 8 elems/thread
// ---------------------------------------------------------------------------
__global__ __launch_bounds__(256)
void f2b(const float* __restrict__ in, bf16_t* __restrict__ out, int n8)
{
    int i = blockIdx.x * 256 + threadIdx.x;
    if (i >= n8) return;
    const float4* p = (const float4*)in + 2 * (size_t)i;
    float4 a = p[0], b = p[1];
    bf16x8 o;
    o[0] = (bf16_t)a.x; o[1] = (bf16_t)a.y; o[2] = (bf16_t)a.z; o[3] = (bf16_t)a.w;
    o[4] = (bf16_t)b.x; o[5] = (bf16_t)b.y; o[6] = (bf16_t)b.z; o[7] = (bf16_t)b.w;
    *((bf16x8*)out + i) = o;
}

// ---------------------------------------------------------------------------
// 256x256 8-wave deep-pipelined GEMM: C[M][N] = A[M][K] * B[N][K]^T (bf16 in).
// Quad-buffered BK=32, prefetch depth 3: tile t stages tile t+3 into buf
// (t+3)&3 (= buf of tile t-1, whose reads were lgkmcnt(0)-drained before
// t-1's closing barrier -> structurally safe). Counted vmcnt(8) at each tile
// end drains tile t+1's loads, issued 6 phases (~2000cy) earlier >> ~900cy
// HBM latency -- never exposes load latency (the round-4 vmcnt(4) window was
// only 2 phases ~ latency, stalling every tile at the m97 ceiling).
// Per phase: {ds_read frags | stage 2x global_load_lds | barrier | lgkmcnt(0)
// | setprio(1) 16xMFMA setprio(0) | barrier}. LDS swizzle: 16B chunk ^=
// (row>>1)&3 within 64B rows -> 2-way reads (free); staged via pre-swizzled
// global source (linear LDS dest).
// ---------------------------------------------------------------------------
#define STAGE_A(b, ks)  do {                                               \
    const char* as_ = Ab + (size_t)srow * Krb + (ks) + scol0;              \
    GLOAD_LDS16(as_,             ldsA[b] + t * 16);                        \
    GLOAD_LDS16(as_ + 128 * Krb, ldsA[b] + 8192 + t * 16);                 \
} while (0)
#define STAGE_B(b, ks)  do {                                               \
    const char* bs_ = Bb + (size_t)srow * Krb + (ks) + scol0;              \
    GLOAD_LDS16(bs_,             ldsB[b] + t * 16);                        \
    GLOAD_LDS16(bs_ + 128 * Krb, ldsB[b] + 8192 + t * 16);                 \
} while (0)
#define LDS_AT(buf, row, lg_) \
    (*(const bf16x8*)((buf) + (row) * 64 + (((lg_) * 16) ^ ((((row) >> 1) & 3) << 4))))

#define TILE(bufi, tno)  do {                                              \
    const int ks3_ = ((tno) + 3 < NT) ? ((tno) + 3) * 64 : 0;              \
    /* ---- phase alpha: A frags + B frags(n=0,1), stage A of t+3 ---- */  \
    bf16x8 af[8], bfr0, bfr1;                                              \
    _Pragma("unroll")                                                      \
    for (int m = 0; m < 8; ++m) {                                          \
        int row = wm * 128 + m * 16 + l15;                                 \
        af[m] = LDS_AT(ldsA[bufi], row, lg);                               \
    }                                                                      \
    { int rb = wn * 64 + l15;      bfr0 = LDS_AT(ldsB[bufi], rb, lg); }    \
    { int rb = wn * 64 + 16 + l15; bfr1 = LDS_AT(ldsB[bufi], rb, lg); }    \
    STAGE_A(((tno) + 3) & 3, ks3_);                                        \
    __builtin_amdgcn_sched_barrier(0);                                     \
    __builtin_amdgcn_s_barrier();                                          \
    asm volatile("s_waitcnt lgkmcnt(0)" ::: "memory");                     \
    __builtin_amdgcn_sched_barrier(0);                                     \
    __builtin_amdgcn_s_setprio(1);                                         \
    _Pragma("unroll")                                                      \
    for (int m = 0; m < 8; ++m) {                                          \
        acc[m][0] = __builtin_amdgcn_mfma_f32_16x16x32_bf16(af[m], bfr0, acc[m][0], 0, 0, 0); \
        acc[m][1] = __builtin_amdgcn_mfma_f32_16x16x32_bf16(af[m], bfr1, acc[m][1], 0, 0, 0); \
    }                                                                      \
    __builtin_amdgcn_s_setprio(0);                                         \
    __builtin_amdgcn_sched_barrier(0);                                     \
    __builtin_amdgcn_s_barrier();                                          \
    /* ---- phase beta: B frags(n=2,3), reuse af, stage B of t+3 ---- */   \
    { int rb = wn * 64 + 32 + l15; bfr0 = LDS_AT(ldsB[bufi], rb, lg); }    \
    { int rb = wn * 64 + 48 + l15; bfr1 = LDS_AT(ldsB[bufi], rb, lg); }    \
    STAGE_B(((tno) + 3) & 3, ks3_);                                        \
    __builtin_amdgcn_sched_barrier(0);                                     \
    __builtin_amdgcn_s_barrier();                                          \
    asm volatile("s_waitcnt lgkmcnt(0)" ::: "memory");                     \
    __builtin_amdgcn_sched_barrier(0);                                     \
    __builtin_amdgcn_s_setprio(1);                                         \
    _Pragma("unroll")                                                      \
    for (int m = 0; m < 8; ++m) {                                          \
        acc[m][2] = __builtin_amdgcn_mfma_f32_16x16x32_bf16(af[m], bfr0, acc[m][2], 0, 0, 0); \
        acc[m][3] = __builtin_amdgcn_mfma_f32_16x16x32_bf16(af[m], bfr1, acc[m][3], 0, 0, 0); \
    }                                                                      \
    __builtin_amdgcn_s_setprio(0);                                         \
    asm volatile("s_waitcnt vmcnt(8)" ::: "memory");                       \
    __builtin_amdgcn_sched_barrier(0);                                     \
    __builtin_amdgcn_s_barrier();                                          \
} while (0)

template<bool OUT_F32>
__global__ __launch_bounds__(512, 2)
void gemm256(const bf16_t* __restrict__ A, const bf16_t* __restrict__ B,
             void* __restrict__ Cv, int M, int N, int K, int nbn)
{
    __shared__ __align__(16) char ldsA[4][16384];   // 4 bufs x 256 rows x 64B
    __shared__ __align__(16) char ldsB[4][16384];

    const int nwg = gridDim.x;
    const int bid0 = blockIdx.x;
    const int bid = (bid0 & 7) * (nwg >> 3) + (bid0 >> 3);   // XCD swizzle
    const int bm = bid / nbn, bn = bid % nbn;
    const int t = threadIdx.x;
    const int lane = t & 63, wid = t >> 6;
    const int wm = wid >> 2, wn = wid & 3;          // 2M x 4N waves
    const int l15 = lane & 15, lg = lane >> 4;
    const int m0 = bm * 256, n0 = bn * 256;

    // staging map: per inst, 512 thr x 16B = 128 rows x 64B; t -> row t>>2, chunk t&3
    const int srow = t >> 2;
    const int scol0 = (((t & 3) ^ ((srow >> 1) & 3)) << 4);  // pre-swizzled src col
    const int Krb = K * 2;                                   // row bytes
    const char* Ab = (const char*)A + (size_t)m0 * Krb;
    const char* Bb = (const char*)B + (size_t)n0 * Krb;

    const int NT = K >> 5;                                   // K-tiles of 32
    f32x4 acc[8][4] = {};

    // prologue: tiles 0,1,2 staged (12 loads); vmcnt(8) -> tile 0 landed
    STAGE_A(0, 0);   STAGE_B(0, 0);
    STAGE_A(1, 64);  STAGE_B(1, 64);
    STAGE_A(2, 128); STAGE_B(2, 128);
    asm volatile("s_waitcnt vmcnt(8)" ::: "memory");
    __builtin_amdgcn_sched_barrier(0);
    __builtin_amdgcn_s_barrier();

    for (int tt = 0; tt < NT; tt += 4) {
        TILE(0, tt + 0);
        TILE(1, tt + 1);
        TILE(2, tt + 2);
        TILE(3, tt + 3);
    }

    // epilogue: D col = lane&15, row = (lane>>4)*4 + i
    #pragma unroll
    for (int m = 0; m < 8; ++m) {
        int row0 = m0 + wm * 128 + m * 16 + lg * 4;
        #pragma unroll
        for (int n = 0; n < 4; ++n) {
            int col = n0 + wn * 64 + n * 16 + l15;
            #pragma unroll
            for (int i = 0; i < 4; ++i) {
                if constexpr (OUT_F32)
                    ((float*)Cv)[(size_t)(row0 + i) * N + col] = acc[m][n][i];
                else
                    ((bf16_t*)Cv)[(size_t)(row0 + i) * N + col] = (bf16_t)acc[m][n][i];
            }
        }
    }
}
#undef TILE
#undef LDS_AT
#undef STAGE_A
#undef STAGE_B

// ---------------------------------------------------------------------------
// 128x128 m97-structure GEMM, kept for the KV projection (N=2048 -> 512
// blocks; a 256 tile would leave half the CUs idle). MODE 2 epilogue splits
// cols <1024 to K buffer, cols >=1024 transposed to Vt[(col-1024)][tok].
// ---------------------------------------------------------------------------
template<int MODE>
__global__ __launch_bounds__(256, 4)
void gemm_bt(const bf16_t* __restrict__ A, const bf16_t* __restrict__ B,
             void* __restrict__ Cv, bf16_t* __restrict__ Vt,
             int M, int N, int K, int nbn)
{
    __shared__ __align__(16) bf16_t lA[128 * 32];
    __shared__ __align__(16) bf16_t lB[128 * 32];

    const int nwg = gridDim.x;
    const int bid0 = blockIdx.x;
    const int bid = (bid0 & 7) * (nwg >> 3) + (bid0 >> 3);
    const int bm = bid / nbn, bn = bid % nbn;
    const int t = threadIdx.x;
    const int lane = t & 63, wid = t >> 6;
    const int wrow = (wid >> 1) * 64, wcol = (wid & 1) * 64;
    const int l15 = lane & 15, lg = lane >> 4;
    const int m0 = bm * 128, n0 = bn * 128;

    const int r0 = t >> 2, pos0 = (t & 3) * 8;
    const int r1 = r0 + 64;

    const bf16_t* Ar0 = A + (size_t)(m0 + r0) * K + pos0;
    const bf16_t* Ar1 = A + (size_t)(m0 + r1) * K + pos0;
    const bf16_t* Br0 = B + (size_t)(n0 + r0) * K + pos0;
    const bf16_t* Br1 = B + (size_t)(n0 + r1) * K + pos0;

    f32x4 acc[4][4] = {};

    for (int k0 = 0; k0 < K; k0 += 32) {
        __syncthreads();
        GLOAD_LDS16(Ar0 + k0, lA + t * 8);
        GLOAD_LDS16(Ar1 + k0, lA + (t + 256) * 8);
        GLOAD_LDS16(Br0 + k0, lB + t * 8);
        GLOAD_LDS16(Br1 + k0, lB + (t + 256) * 8);
        __syncthreads();

        bf16x8 af[4], bfr[4];
        #pragma unroll
        for (int m = 0; m < 4; ++m)
            af[m] = *(const bf16x8*)(lA + (wrow + m * 16 + l15) * 32 + lg * 8);
        #pragma unroll
        for (int n = 0; n < 4; ++n)
            bfr[n] = *(const bf16x8*)(lB + (wcol + n * 16 + l15) * 32 + lg * 8);
        #pragma unroll
        for (int m = 0; m < 4; ++m)
            #pragma unroll
            for (int n = 0; n < 4; ++n)
                acc[m][n] = __builtin_amdgcn_mfma_f32_16x16x32_bf16(
                    af[m], bfr[n], acc[m][n], 0, 0, 0);
    }

    #pragma unroll
    for (int m = 0; m < 4; ++m) {
        #pragma unroll
        for (int n = 0; n < 4; ++n) {
            int col  = n0 + wcol + n * 16 + l15;
            int row0 = m0 + wrow + m * 16 + lg * 4;
            if constexpr (MODE == 0) {
                #pragma unroll
                for (int i = 0; i < 4; ++i)
                    ((bf16_t*)Cv)[(size_t)(row0 + i) * N + col] = (bf16_t)acc[m][n][i];
            } else if constexpr (MODE == 1) {
                #pragma unroll
                for (int i = 0; i < 4; ++i)
                    ((float*)Cv)[(size_t)(row0 + i) * N + col] = acc[m][n][i];
            } else {
                if (col < 1024) {
                    #pragma unroll
                    for (int i = 0; i < 4; ++i)
                        ((bf16_t*)Cv)[(size_t)(row0 + i) * 1024 + col] = (bf16_t)acc[m][n][i];
                } else {
                    bf16x4 pk;
                    #pragma unroll
                    for (int i = 0; i < 4; ++i) pk[i] = (bf16_t)acc[m][n][i];
                    *(bf16x4*)(Vt + (size_t)(col - 1024) * 4096 + row0) = pk;
                }
            }
        }
    }
}

// ---------------------------------------------------------------------------
// RoPE (interleaved pairs), in-place on bf16, 8 elems (4 pairs) per thread.
// ---------------------------------------------------------------------------
__global__ __launch_bounds__(256)
void rope_kernel(bf16_t* __restrict__ X, const float* __restrict__ fc,
                 const float* __restrict__ fs, int nheads, int rowstride)
{
    int idx = blockIdx.x * 256 + threadIdx.x;
    int j4 = idx & 15;
    int rest = idx >> 4;
    int h = rest % nheads;
    int tok = rest / nheads;
    int s = tok & (SEQ - 1);
    bf16_t* p = X + (size_t)tok * rowstride + h * HDIM + j4 * 8;
    bf16x8 v = *(const bf16x8*)p;
    float4 c  = *(const float4*)(fc + s * 64 + j4 * 4);
    float4 sn = *(const float4*)(fs + s * 64 + j4 * 4);
    bf16x8 o;
    o[0] = (bf16_t)((float)v[0] * c.x - (float)v[1] * sn.x);
    o[1] = (bf16_t)((float)v[0] * sn.x + (float)v[1] * c.x);
    o[2] = (bf16_t)((float)v[2] * c.y - (float)v[3] * sn.y);
    o[3] = (bf16_t)((float)v[2] * sn.y + (float)v[3] * c.y);
    o[4] = (bf16_t)((float)v[4] * c.z - (float)v[5] * sn.z);
    o[5] = (bf16_t)((float)v[4] * sn.z + (float)v[5] * c.z);
    o[6] = (bf16_t)((float)v[6] * c.w - (float)v[7] * sn.w);
    o[7] = (bf16_t)((float)v[6] * sn.w + (float)v[7] * c.w);
    *(bf16x8*)p = o;
}

// ---------------------------------------------------------------------------
// Flash attention (non-causal), GQA 4:1.
// K: [tok][kv*128+d] (stride 1024). Vt: [kv*128+d][tok] (stride 4096).
// global_load_lds staging with pre-swizzled source; swapped QK^T; in-register
// softmax; P^T regs feed 16x16x16 MFMA. 32KB LDS, 4 blocks/CU.
// ---------------------------------------------------------------------------
__global__ __launch_bounds__(256, 4)
void attn_kernel(const bf16_t* __restrict__ Q, const bf16_t* __restrict__ Kg,
                 const bf16_t* __restrict__ Vtg, bf16_t* __restrict__ O)
{
    __shared__ __align__(16) char klds[64 * 256];    // K tile [key][d], swizzled
    __shared__ __align__(16) char vlds[128 * 128];   // V^T tile [d][key], swizzled

    const int nwg = gridDim.x;
    const int bid0 = blockIdx.x;
    const int blk = (bid0 & 7) * (nwg >> 3) + (bid0 >> 3);
    const int qt = blk & 15;
    const int bh = blk >> 4;
    const int b = bh >> 5, h = bh & 31, kv = h >> 2;
    const int t = threadIdx.x, lane = t & 63, wid = t >> 6;
    const int l15 = lane & 15, lg = lane >> 4;
    const int swzk = (l15 & 7) << 4;

    const float SCL = 0.08838834764831845f;
    const float L2E = 1.4426950408889634f;

    const int qrow = qt * 64 + wid * 16 + l15;
    const size_t qbase = (size_t)(b * SEQ + qrow) * DMODEL + h * HDIM;
    bf16x8 qf[4];
    #pragma unroll
    for (int dc = 0; dc < 4; ++dc)
        qf[dc] = *(const bf16x8*)(Q + qbase + dc * 32 + lg * 8);

    const char* kgb = (const char*)Kg + ((size_t)(b * SEQ) * 1024 + kv * HDIM) * 2;
    const char* vgb = (const char*)Vtg + ((size_t)(kv * HDIM) * 4096 + b * SEQ) * 2;

    f32x4 o[8] = {};
    float mrun = -3.0e38f, lrun = 0.f;

    for (int kt = 0; kt < 16; ++kt) {
        __syncthreads();
        #pragma unroll
        for (int i = 0; i < 4; ++i) {
            int idx = t + 256 * i;
            {
                int r = idx >> 4, cb = (idx & 15) << 4;
                const char* src = kgb + (size_t)(kt * 64 + r) * 2048
                                      + (cb ^ ((r & 7) << 4));
                GLOAD_LDS16(src, klds + idx * 16);
            }
            {
                int d = idx >> 3, cb = (idx & 7) << 4;
                const char* src = vgb + (size_t)d * 8192 + kt * 128
                                      + (cb ^ ((d & 7) << 4));
                GLOAD_LDS16(src, vlds + idx * 16);
            }
        }
        __syncthreads();

        f32x4 sacc[4] = {};
        #pragma unroll
        for (int kb = 0; kb < 4; ++kb) {
            const char* krow = klds + (kb * 16 + l15) * 256;
            #pragma unroll
            for (int dc = 0; dc < 4; ++dc) {
                bf16x8 kf = *(const bf16x8*)(krow + ((dc * 64 + lg * 16) ^ swzk));
                sacc[kb] = __builtin_amdgcn_mfma_f32_16x16x32_bf16(
                    kf, qf[dc], sacc[kb], 0, 0, 0);
            }
        }

        float sv[16];
        float mt = -3.0e38f;
        #pragma unroll
        for (int kb = 0; kb < 4; ++kb)
            #pragma unroll
            for (int i = 0; i < 4; ++i) {
                float s = sacc[kb][i] * SCL;
                sv[kb * 4 + i] = s;
                mt = fmaxf(mt, s);
            }
        mt = fmaxf(mt, __shfl_xor(mt, 16));
        mt = fmaxf(mt, __shfl_xor(mt, 32));
        float mnew = fmaxf(mrun, mt);
        float alpha = exp2f((mrun - mnew) * L2E);

        float ts = 0.f;
        s16x4 pf[4];
        #pragma unroll
        for (int kb = 0; kb < 4; ++kb)
            #pragma unroll
            for (int i = 0; i < 4; ++i) {
                float p = exp2f((sv[kb * 4 + i] - mnew) * L2E);
                ts += p;
                pf[kb][i] = (short)__builtin_bit_cast(unsigned short, (bf16_t)p);
            }
        ts += __shfl_xor(ts, 16);
        ts += __shfl_xor(ts, 32);
        lrun = lrun * alpha + ts;
        mrun = mnew;

        #pragma unroll
        for (int i = 0; i < 4; ++i) {
            float ai = __shfl(alpha, lg * 4 + i);
            #pragma unroll
            for (int db = 0; db < 8; ++db) o[db][i] *= ai;
        }

        #pragma unroll
        for (int kb = 0; kb < 4; ++kb)
            #pragma unroll
            for (int db = 0; db < 8; ++db) {
                int d = l15 + 16 * db;
                const char* va = vlds + d * 128 + ((kb * 32 + lg * 8) ^ swzk);
                s16x4 vf = *(const s16x4*)va;
                o[db] = __builtin_amdgcn_mfma_f32_16x16x16bf16_1k(
                    pf[kb], vf, o[db], 0, 0, 0);
            }
    }

    #pragma unroll
    for (int i = 0; i < 4; ++i) {
        float li = __shfl(lrun, lg * 4 + i);
        float inv = 1.0f / li;
        int row = b * SEQ + qt * 64 + wid * 16 + lg * 4 + i;
        #pragma unroll
        for (int db = 0; db < 8; ++db) {
            int col = h * HDIM + l15 + 16 * db;
            O[(size_t)row * DMODEL + col] = (bf16_t)(o[db][i] * inv);
        }
    }
}

// ---------------------------------------------------------------------------
// Launch. Workspace (bf16): Qw 32M | Kw2 8M | Vt 8M | AO 32M | xb 32M |
// wqb 32M | wkvb 16M | wob 32M = 192 MiB.
// ---------------------------------------------------------------------------
extern "C" void kernel_launch(void* const* d_in, const int* in_sizes, int n_in,
                              void* d_out, int out_size, void* d_ws, size_t ws_size,
                              hipStream_t stream)
{
    const float* x  = (const float*)d_in[0];
    const float* wq = (const float*)d_in[1];
    const float* wk = (const float*)d_in[2];
    const float* wv = (const float*)d_in[3];
    const float* wo = (const float*)d_in[4];
    const float* fc = (const float*)d_in[5];
    const float* fs = (const float*)d_in[6];

    const size_t T = (size_t)4096;
    bf16_t* Qw   = (bf16_t*)d_ws;            // [4096][4096]
    bf16_t* Kw2  = Qw   + T * 4096;          // [4096][1024]
    bf16_t* Vt   = Kw2  + T * 1024;          // [1024(kv*128+d)][4096 tok]
    bf16_t* AO   = Vt   + T * 1024;          // [4096][4096]
    bf16_t* xb   = AO   + T * 4096;          // [4096][4096]
    bf16_t* wqb  = xb   + T * 4096;          // [4096][4096]
    bf16_t* wkvb = wqb  + T * 4096;          // [2048][4096]  (wk ; wv)
    bf16_t* wob  = wkvb + T * 2048;          // [4096][4096]

    f2b<<<8192, 256, 0, stream>>>(x,  xb,  4096 * 4096 / 8);
    f2b<<<8192, 256, 0, stream>>>(wq, wqb, 4096 * 4096 / 8);
    f2b<<<2048, 256, 0, stream>>>(wk, wkvb,                       1024 * 4096 / 8);
    f2b<<<2048, 256, 0, stream>>>(wv, wkvb + (size_t)1024 * 4096, 1024 * 4096 / 8);
    f2b<<<8192, 256, 0, stream>>>(wo, wob, 4096 * 4096 / 8);

    gemm256<false><<<256, 512, 0, stream>>>(xb, wqb, Qw, 4096, 4096, 4096, 16);
    gemm_bt<2><<<512, 256, 0, stream>>>(xb, wkvb, Kw2, Vt, 4096, 2048, 4096, 16);

    rope_kernel<<<8192, 256, 0, stream>>>(Qw,  fc, fs, NHQ,  4096);
    rope_kernel<<<2048, 256, 0, stream>>>(Kw2, fc, fs, NHKV, 1024);

    attn_kernel<<<2048, 256, 0, stream>>>(Qw, Kw2, Vt, AO);

    gemm256<true><<<256, 512, 0, stream>>>(AO, wob, d_out, 4096, 4096, 4096, 16);
}